// Round 1
// baseline (164.586 us; speedup 1.0000x reference)
//
#include <hip/hip_runtime.h>
#include <hip/hip_bf16.h>

// MSA: B=4, S=2048, D=256, H=8, DH=32
// q/k/v = seq @ W[h] + b[h]  (per-head full-token linear maps)
// out = softmax(q k^T / sqrt(32)) v, heads hstacked -> [B,S,D] f32

#define NB 4
#define NS 2048
#define ND 256
#define NH 8
#define NDH 32

typedef __attribute__((ext_vector_type(8))) short short8;
typedef __attribute__((ext_vector_type(4))) float float4v;

static __device__ __forceinline__ unsigned short f2bf(float f) {
    union { float f; unsigned int u; } v; v.f = f;
    unsigned int r = (v.u + 0x7FFFu + ((v.u >> 16) & 1u)) >> 16;
    return (unsigned short)r;
}

// ---------------- prep: sequences f32 -> bf16 ----------------
__global__ __launch_bounds__(256) void prep_seq(const float* __restrict__ seq,
                                                unsigned short* __restrict__ seqb) {
    int i = (blockIdx.x * 256 + threadIdx.x) * 4;  // 2M elems / 4
    float4 v = *(const float4*)(seq + i);
    ushort4 o;
    o.x = f2bf(v.x); o.y = f2bf(v.y); o.z = f2bf(v.z); o.w = f2bf(v.w);
    *(ushort4*)(seqb + i) = o;
}

// ---------------- prep: W[h][d][e] -> Wt[c][d] bf16 (c = mat*256 + h*32 + e) ----------------
__global__ __launch_bounds__(256) void prep_w(const float* __restrict__ Wq,
                                              const float* __restrict__ Wk,
                                              const float* __restrict__ Wv,
                                              unsigned short* __restrict__ Wt) {
    int idx = blockIdx.x * 256 + threadIdx.x;      // 768*256
    int c = idx >> 8, d = idx & 255;
    int mat = c >> 8;
    int cm = c & 255;
    int h = cm >> 5, e = cm & 31;
    const float* W = (mat == 0) ? Wq : (mat == 1) ? Wk : Wv;
    Wt[c * 256 + d] = f2bf(W[(h * 256 + d) * 32 + e]);
}

// ---------------- projection GEMM: M=8192, N=768, K=256 ----------------
// Q,K out: [BH][S][32] bf16 ; V out transposed: [BH][32][S] bf16. Bias fused.
__global__ __launch_bounds__(256) void proj(const unsigned short* __restrict__ seqb,
                                            const unsigned short* __restrict__ Wt,
                                            const float* __restrict__ bq,
                                            const float* __restrict__ bk,
                                            const float* __restrict__ bv,
                                            unsigned short* __restrict__ Q,
                                            unsigned short* __restrict__ K,
                                            unsigned short* __restrict__ Vt) {
    int m0 = blockIdx.x * 64;        // 128 blocks
    int c0 = blockIdx.y * 64;        // 12 blocks (64-col tiles never cross a matrix boundary)
    int wave = threadIdx.x >> 6, lane = threadIdx.x & 63;
    int g = lane >> 4, r4 = lane & 15;
    int mrow = m0 + wave * 16 + r4;

    float4v acc0 = {0.f, 0.f, 0.f, 0.f};
    float4v acc1 = {0.f, 0.f, 0.f, 0.f};
    float4v acc2 = {0.f, 0.f, 0.f, 0.f};
    float4v acc3 = {0.f, 0.f, 0.f, 0.f};

    const unsigned short* arow = seqb + mrow * 256 + 8 * g;
    const unsigned short* b0 = Wt + (c0 + 0 * 16 + r4) * 256 + 8 * g;
    const unsigned short* b1 = Wt + (c0 + 1 * 16 + r4) * 256 + 8 * g;
    const unsigned short* b2 = Wt + (c0 + 2 * 16 + r4) * 256 + 8 * g;
    const unsigned short* b3 = Wt + (c0 + 3 * 16 + r4) * 256 + 8 * g;

#pragma unroll
    for (int d0 = 0; d0 < 256; d0 += 32) {
        short8 a = *(const short8*)(arow + d0);
        acc0 = __builtin_amdgcn_mfma_f32_16x16x32_bf16(a, *(const short8*)(b0 + d0), acc0, 0, 0, 0);
        acc1 = __builtin_amdgcn_mfma_f32_16x16x32_bf16(a, *(const short8*)(b1 + d0), acc1, 0, 0, 0);
        acc2 = __builtin_amdgcn_mfma_f32_16x16x32_bf16(a, *(const short8*)(b2 + d0), acc2, 0, 0, 0);
        acc3 = __builtin_amdgcn_mfma_f32_16x16x32_bf16(a, *(const short8*)(b3 + d0), acc3, 0, 0, 0);
    }

    float4v accs[4] = {acc0, acc1, acc2, acc3};
#pragma unroll
    for (int ct = 0; ct < 4; ++ct) {
        int c = c0 + ct * 16 + r4;
        int mat = c >> 8;
        int cm = c & 255;
        int h = cm >> 5, e = cm & 31;
        float bias = ((mat == 0) ? bq : (mat == 1) ? bk : bv)[cm];
#pragma unroll
        for (int r = 0; r < 4; ++r) {
            int m = m0 + wave * 16 + 4 * g + r;
            int b = m >> 11, s = m & 2047;
            unsigned short val = f2bf(accs[ct][r] + bias);
            if (mat == 0)      Q[((b * NH + h) * NS + s) * NDH + e] = val;
            else if (mat == 1) K[((b * NH + h) * NS + s) * NDH + e] = val;
            else               Vt[((b * NH + h) * NDH + e) * NS + s] = val;
        }
    }
}

// ---------------- flash attention ----------------
// grid: 32 (bh) * 32 (q-tiles of 64) ; block: 256 = 4 waves * 16 q-rows
__global__ __launch_bounds__(256) void attn_kernel(const unsigned short* __restrict__ Q,
                                                   const unsigned short* __restrict__ K,
                                                   const unsigned short* __restrict__ Vt,
                                                   float* __restrict__ out) {
    __shared__ unsigned short Plds[4][16][40];  // per-wave P tile, rows padded to 40 (16B-aligned)

    int bh = blockIdx.x >> 5;
    int qt = blockIdx.x & 31;
    int wave = threadIdx.x >> 6, lane = threadIdx.x & 63;
    int g = lane >> 4, r4 = lane & 15;
    int q0 = qt * 64 + wave * 16;

    const unsigned short* Qb = Q + (bh * NS) * NDH;
    const unsigned short* Kb = K + (bh * NS) * NDH;
    const unsigned short* Vb = Vt + (bh * NDH) * NS;

    // Q fragment: lane holds Q[q0 + r4][8g .. 8g+7]
    short8 aq = *(const short8*)(Qb + (q0 + r4) * NDH + 8 * g);

    float m_run[4] = {-3e38f, -3e38f, -3e38f, -3e38f};
    float l_run[4] = {0.f, 0.f, 0.f, 0.f};
    float4v accA = {0.f, 0.f, 0.f, 0.f};  // dh 0..15 (col = r4)
    float4v accB = {0.f, 0.f, 0.f, 0.f};  // dh 16..31
    const float scale = 0.17677669529663687f;  // 1/sqrt(32)

    for (int k0 = 0; k0 < NS; k0 += 32) {
        short8 kf0 = *(const short8*)(Kb + (k0 + r4) * NDH + 8 * g);
        short8 kf1 = *(const short8*)(Kb + (k0 + 16 + r4) * NDH + 8 * g);
        float4v zero = {0.f, 0.f, 0.f, 0.f};
        // scores: D[q=4g+r][key=r4 (+16)]
        float4v s0 = __builtin_amdgcn_mfma_f32_16x16x32_bf16(aq, kf0, zero, 0, 0, 0);
        float4v s1 = __builtin_amdgcn_mfma_f32_16x16x32_bf16(aq, kf1, zero, 0, 0, 0);

        float mx[4];
#pragma unroll
        for (int r = 0; r < 4; ++r) {
            s0[r] *= scale; s1[r] *= scale;
            mx[r] = fmaxf(s0[r], s1[r]);
        }
        // row max across the 16 key-lanes of this group
#pragma unroll
        for (int off = 1; off < 16; off <<= 1) {
#pragma unroll
            for (int r = 0; r < 4; ++r) mx[r] = fmaxf(mx[r], __shfl_xor(mx[r], off));
        }

        float p0[4], p1[4], sum[4], al[4];
#pragma unroll
        for (int r = 0; r < 4; ++r) {
            float mn = fmaxf(m_run[r], mx[r]);
            al[r] = __expf(m_run[r] - mn);
            p0[r] = __expf(s0[r] - mn);
            p1[r] = __expf(s1[r] - mn);
            sum[r] = p0[r] + p1[r];
            m_run[r] = mn;
        }
#pragma unroll
        for (int off = 1; off < 16; off <<= 1) {
#pragma unroll
            for (int r = 0; r < 4; ++r) sum[r] += __shfl_xor(sum[r], off);
        }
#pragma unroll
        for (int r = 0; r < 4; ++r) {
            l_run[r] = l_run[r] * al[r] + sum[r];
            accA[r] *= al[r];
            accB[r] *= al[r];
            Plds[wave][4 * g + r][r4] = f2bf(p0[r]);
            Plds[wave][4 * g + r][16 + r4] = f2bf(p1[r]);
        }

        // PV: A = P[q=r4][key 8g..8g+7] from LDS; B = Vt[dh][key] fragments
        short8 pa = *(const short8*)(&Plds[wave][r4][8 * g]);
        short8 v0 = *(const short8*)(Vb + r4 * NS + k0 + 8 * g);
        short8 v1 = *(const short8*)(Vb + (16 + r4) * NS + k0 + 8 * g);
        accA = __builtin_amdgcn_mfma_f32_16x16x32_bf16(pa, v0, accA, 0, 0, 0);
        accB = __builtin_amdgcn_mfma_f32_16x16x32_bf16(pa, v1, accB, 0, 0, 0);
    }

    int b = bh >> 3, h = bh & 7;
#pragma unroll
    for (int r = 0; r < 4; ++r) {
        float inv = 1.0f / l_run[r];
        int s = q0 + 4 * g + r;
        float* op = out + (b * NS + s) * ND + h * NDH;
        op[r4] = accA[r] * inv;
        op[16 + r4] = accB[r] * inv;
    }
}

extern "C" void kernel_launch(void* const* d_in, const int* in_sizes, int n_in,
                              void* d_out, int out_size, void* d_ws, size_t ws_size,
                              hipStream_t stream) {
    const float* seq = (const float*)d_in[0];
    const float* Wq = (const float*)d_in[1];
    const float* Wk = (const float*)d_in[2];
    const float* Wv = (const float*)d_in[3];
    const float* bq = (const float*)d_in[4];
    const float* bk = (const float*)d_in[5];
    const float* bv = (const float*)d_in[6];
    float* out = (float*)d_out;

    // workspace layout (bf16 elements): seqb 2M | Wt 196608 | Q 2M | K 2M | Vt 2M  (~17.2 MB)
    unsigned short* seqb = (unsigned short*)d_ws;
    unsigned short* Wt = seqb + 2097152;
    unsigned short* Qw = Wt + 196608;
    unsigned short* Kw = Qw + 2097152;
    unsigned short* Vtw = Kw + 2097152;

    hipLaunchKernelGGL(prep_seq, dim3(2048), dim3(256), 0, stream, seq, seqb);
    hipLaunchKernelGGL(prep_w, dim3(768), dim3(256), 0, stream, Wq, Wk, Wv, Wt);
    hipLaunchKernelGGL(proj, dim3(128, 12), dim3(256), 0, stream, seqb, Wt, bq, bk, bv, Qw, Kw, Vtw);
    hipLaunchKernelGGL(attn_kernel, dim3(1024), dim3(256), 0, stream, Qw, Kw, Vtw, out);
}